// Round 4
// baseline (95.082 us; speedup 1.0000x reference)
//
#include <hip/hip_runtime.h>
#include <math.h>
#include <stdint.h>

// SemiConv2d tropical conv: out = max_{ic,kh,kw} min(x_pad, K). f16-packed.
// R17: 2-DEEP SOFTWARE PIPELINE on R16's compact layout. R16 post-mortem:
// -9.4us (predicted -10..-16) but R16 also DROPPED R13/R14's table
// prefetch -> per-iter serial chain s_load(~200cy) -> addr -> vload
// (~200cy) -> VALU(~76cy) ~= 500cy x 12 iters, only 6 waves/SIMD to hide
// it => main is LATENCY-bound (throughput floors: VALU ~7us, L1 ~12us,
// L2 bytes ~6.5us; measured ~33us). R17 pipeline: at iter c, entries
// (SGPR) for c+1 loaded at c-1; vector data for c in flight since c-1;
// this iter issues vloads(c+1) + s_load(c+2) BEFORE computing. Per-iter
// cost -> max(VALU 76cy, issue) ~ 100cy. Exit compare in f16 (no cvt),
// threshold kn rides in prefetched group. Setup identical to R16.
// Predict: main ~33 -> 12-16us, total 89.3 -> 72-78us, absmax exactly
// 0.015625. If >=85: loop is L1/TA-throughput-bound -> next halves load
// instr count (wider lanes / 2 output-pairs per lane).
// Budget model: ~43us harness ws re-poison fill (268MB, irreducible) +
// setup ~8 + main + launch gaps.

#define HH 96
#define WW 96
#define CIN 32
#define OCN 32
#define XQ_ROWS 98
#define ROWB 200                                // bytes per padded row (98 f16 + pad)
#define SLICEB (XQ_ROWS * ROWB)                 // 19600 B per (n,ic) slice
#define XQ_BYTES ((size_t)256 * SLICEB)         // 5,017,600 B
#define ROWU2 25                                // uint2 (8B) per row
#define XQW_TOTAL (256 * XQ_ROWS * ROWU2)       // 627,200 setup threads
#define XQWB (XQW_TOTAL / 256)                  // 2450 pack blocks
#define NROW 96                                 // sorted row-entries per oc
#define NGRP (NROW / 4)                         // 24 groups of 4 rows
#define TBL_BYTES ((size_t)OCN * NROW * 16)
#define RMX_BYTES ((size_t)OCN * NROW * 4)
#define WS_NEED (XQ_BYTES + TBL_BYTES + RMX_BYTES)
#define NEGH2 0xFC00FC00u

typedef _Float16 h2 __attribute__((ext_vector_type(2)));
typedef uint32_t u2a4 __attribute__((ext_vector_type(2), aligned(4)));

__device__ __forceinline__ uint32_t pkmin_vs(uint32_t x, uint32_t k) {
    uint32_t d;
    asm("v_pk_min_f16 %0, %1, %2" : "=v"(d) : "v"(x), "s"(k));
    return d;
}
__device__ __forceinline__ uint32_t pkmin_vv(uint32_t a, uint32_t b) {
    uint32_t d;
    asm("v_pk_min_f16 %0, %1, %2" : "=v"(d) : "v"(a), "v"(b));
    return d;
}
__device__ __forceinline__ uint32_t pkmax(uint32_t a, uint32_t b) {
    uint32_t d;
    asm("v_pk_max_f16 %0, %1, %2" : "=v"(d) : "v"(a), "v"(b));
    return d;
}
__device__ __forceinline__ uint32_t packh2(float lo, float hi) {
    h2 p = {(_Float16)lo, (_Float16)hi};
    return __builtin_bit_cast(uint32_t, p);
}

// Fused setup (identical to R16).
// Blocks [0, XQWB): pack x -> compact xq. Row (s, hp): 98 f16 covering
//   w = -1..96 at bytes 0..195 (+4B pad), value = x[s][hp-1][w] or -inf.
// Blocks [XQWB, XQWB+32): per-oc row table sorted by rowmax desc.
//   entry uint4 = {k0dup, k1dup, k2dup, byte_off of (ic,dh) row}
//   rmx[rank]  = rowmax dup (exit threshold bounds all remaining k).
__global__ __launch_bounds__(256) void setup_all(const float* __restrict__ x,
                                                 const float* __restrict__ kk,
                                                 uint2* __restrict__ xq,
                                                 uint4* __restrict__ tbl,
                                                 uint32_t* __restrict__ rmx) {
    __shared__ float rs[NROW];
    const int bb = blockIdx.x;
    if (bb < XQWB) {
        int idx = bb * 256 + threadIdx.x;       // over 256*98*25
        int j8 = idx % ROWU2;                   // 8B unit in row
        int t  = idx / ROWU2;
        int hp = t % XQ_ROWS;
        int s  = t / XQ_ROWS;
        int h  = hp - 1;
        bool hv = (h >= 0) && (h < HH);
        const float* row = x + ((size_t)s * HH + (hv ? h : 0)) * WW;
        float v[4];
#pragma unroll
        for (int q = 0; q < 4; ++q) {
            int w = 4 * j8 - 1 + q;
            v[q] = (hv && w >= 0 && w < WW) ? row[w] : -INFINITY;
        }
        uint2 o;
        o.x = packh2(v[0], v[1]);
        o.y = packh2(v[2], v[3]);
        xq[idx] = o;
        return;
    }
    // ---- table path ----
    const int oc = bb - XQWB;
    const int t  = threadIdx.x;
    if (t >= NROW) return;
    const int ic = t / 3, dh = t - 3 * ic;
    const float* kp = kk + ((size_t)(oc * CIN + ic) * 3 + dh) * 3;
    float k0 = kp[0], k1 = kp[1], k2 = kp[2];
    float rm = fmaxf(fmaxf(k0, k1), k2);
    rs[t] = rm;
    __syncthreads();
    int rank = 0;
    for (int s = 0; s < NROW; ++s) {
        float v = rs[s];
        rank += (v > rm) || (v == rm && s < t);
    }
    uint32_t off = (uint32_t)(ic * XQ_ROWS + dh) * ROWB;
    tbl[oc * NROW + rank] = make_uint4(packh2(k0, k0), packh2(k1, k1),
                                       packh2(k2, k2), off);
    rmx[oc * NROW + rank] = packh2(rm, rm);
}

__global__ __launch_bounds__(192, 8) void semiconv_p(const char* __restrict__ xqb,
                                                     const uint4* __restrict__ tbl,
                                                     const uint32_t* __restrict__ rmx,
                                                     float* __restrict__ out) {
    const int tid = threadIdx.x;
    const int jj = tid % 48;          // w-pair 0..47
    const int hr = tid / 48;          // 0..3
    const int b  = blockIdx.x;
    const int hp = b % 24;            // hp FASTEST -> XCD spread + L2 locality
    const int t  = b / 24;
    const int oc = t & 31;
    const int n  = t >> 5;
    const int h  = hp * 4 + hr;       // one output row per thread (2 w)

    const char* xqn = xqb + (size_t)n * CIN * SLICEB;   // uniform
    const int vbyte = h * ROWB + 4 * jj;                // per-lane
    const uint4* tb = tbl + oc * NROW;
    const uint32_t* rb = rmx + oc * NROW;

    uint32_t acc = NEGH2;

    // ---- pipeline prologue ----
    // current entries (group 0) + its vector loads in flight
    uint4 cA = tb[0], cB = tb[1], cC = tb[2], cD = tb[3];
    u2a4 q0 = *(const u2a4*)(xqn + cA.w + vbyte);
    u2a4 q1 = *(const u2a4*)(xqn + cB.w + vbyte);
    u2a4 q2 = *(const u2a4*)(xqn + cC.w + vbyte);
    u2a4 q3 = *(const u2a4*)(xqn + cD.w + vbyte);
    // next entries (group 1)
    uint4 nA = tb[4], nB = tb[5], nC = tb[6], nD = tb[7];
    uint32_t nkn = rb[4];             // threshold covering rows >= 4

    for (int c = 0; c < NGRP; ++c) {
        u2a4 p0, p1, p2, p3;
        uint4 fA, fB, fC, fD;
        uint32_t fkn;
        if (c < NGRP - 1) {           // issue NEXT group's vector loads now
            p0 = *(const u2a4*)(xqn + nA.w + vbyte);
            p1 = *(const u2a4*)(xqn + nB.w + vbyte);
            p2 = *(const u2a4*)(xqn + nC.w + vbyte);
            p3 = *(const u2a4*)(xqn + nD.w + vbyte);
        }
        if (c < NGRP - 2) {           // s_load entries for c+2
            const uint4* nb = tb + 4 * (c + 2);
            fA = nb[0]; fB = nb[1]; fC = nb[2]; fD = nb[3];
            fkn = rb[4 * (c + 2)];
        }
        // compute on group c (data already in flight since last iter)
        uint32_t v0 = __builtin_amdgcn_alignbit(q0.y, q0.x, 16);
        uint32_t v1 = __builtin_amdgcn_alignbit(q1.y, q1.x, 16);
        uint32_t v2 = __builtin_amdgcn_alignbit(q2.y, q2.x, 16);
        uint32_t v3 = __builtin_amdgcn_alignbit(q3.y, q3.x, 16);
        uint32_t m0 = pkmax(pkmax(pkmin_vs(q0.x, cA.x), pkmin_vs(v0, cA.y)),
                            pkmin_vs(q0.y, cA.z));
        uint32_t m1 = pkmax(pkmax(pkmin_vs(q1.x, cB.x), pkmin_vs(v1, cB.y)),
                            pkmin_vs(q1.y, cB.z));
        uint32_t m2 = pkmax(pkmax(pkmin_vs(q2.x, cC.x), pkmin_vs(v2, cC.y)),
                            pkmin_vs(q2.y, cC.z));
        uint32_t m3 = pkmax(pkmax(pkmin_vs(q3.x, cD.x), pkmin_vs(v3, cD.y)),
                            pkmin_vs(q3.y, cD.z));
        acc = pkmax(acc, pkmax(pkmax(m0, m1), pkmax(m2, m3)));

        if (c < NGRP - 1) {
            // done iff min(acc.lo, acc.hi) >= next rowmax (max of remaining)
            uint32_t sw = __builtin_amdgcn_alignbit(acc, acc, 16);
            uint32_t mn = pkmin_vv(acc, sw);
            h2 a  = __builtin_bit_cast(h2, mn);
            h2 kv = __builtin_bit_cast(h2, nkn);
            if (__all(a.x >= kv.x)) break;
            // rotate pipeline
            cA = nA; cB = nB; cC = nC; cD = nD;
            q0 = p0; q1 = p1; q2 = p2; q3 = p3;
            nA = fA; nB = fB; nC = fC; nD = fD;
            nkn = fkn;
        }
    }

    h2 a = __builtin_bit_cast(h2, acc);
    float2 v = make_float2((float)a.x, (float)a.y);
    *(float2*)(out + (((size_t)(n * OCN + oc)) * HH + h) * WW + 2 * jj) = v;
}

// ---------- f32 fallback if ws is too small ----------
#define NEGINF (-INFINITY)
__global__ __launch_bounds__(192, 8) void semiconv2d_f32(
    const float* __restrict__ x, const float* __restrict__ kk, float* __restrict__ out)
{
    const int tid = threadIdx.x;
    const int w  = tid % WW;
    const int hr = tid / WW;
    const int b   = blockIdx.x;
    const int ocb = b & 7;
    const int hp  = (b >> 3) % 48;
    const int n   = (b >> 3) / 48;
    const int h   = hp * 2 + hr;
    const int oc0 = ocb * 4;
    float a0[4], a1[4], a2[4];
#pragma unroll
    for (int i = 0; i < 4; ++i) { a0[i] = NEGINF; a1[i] = NEGINF; a2[i] = NEGINF; }
    const bool vm = (h > 0), vp = (h < HH - 1);
    const int hm  = vm ? h - 1 : h;
    const int hpl = vp ? h + 1 : h;
    const int cm  = (w > 0) ? -1 : 0;
    const int cp  = (w < WW - 1) ? 1 : 0;
    const float* rm = x + ((size_t)(n * CIN) * HH + hm)  * WW + w;
    const float* r1 = x + ((size_t)(n * CIN) * HH + h)   * WW + w;
    const float* rp = x + ((size_t)(n * CIN) * HH + hpl) * WW + w;
#pragma unroll 2
    for (int ic = 0; ic < CIN; ++ic) {
        float r00 = vm ? rm[cm] : NEGINF, r01 = vm ? rm[0] : NEGINF, r02 = vm ? rm[cp] : NEGINF;
        float r10 = r1[cm], r11 = r1[0], r12 = r1[cp];
        float r20 = vp ? rp[cm] : NEGINF, r21 = vp ? rp[0] : NEGINF, r22 = vp ? rp[cp] : NEGINF;
#pragma unroll
        for (int oc = 0; oc < 4; ++oc) {
            const float* kq = kk + (size_t)(((oc0 + oc) * CIN + ic)) * 9;
            a0[oc] = fmaxf(fmaxf(a0[oc], fminf(r00, kq[0])), fmaxf(fminf(r10, kq[3]), fminf(r20, kq[6])));
            a1[oc] = fmaxf(fmaxf(a1[oc], fminf(r01, kq[1])), fmaxf(fminf(r11, kq[4]), fminf(r21, kq[7])));
            a2[oc] = fmaxf(fmaxf(a2[oc], fminf(r02, kq[2])), fmaxf(fminf(r12, kq[5]), fminf(r22, kq[8])));
        }
        rm += HH * WW; r1 += HH * WW; rp += HH * WW;
    }
#pragma unroll
    for (int oc = 0; oc < 4; ++oc) {
        float v0 = (w > 0)      ? a0[oc] : NEGINF;
        float v2 = (w < WW - 1) ? a2[oc] : NEGINF;
        out[(((size_t)(n * OCN + oc0 + oc)) * HH + h) * WW + w] = fmaxf(fmaxf(v0, a1[oc]), v2);
    }
}

extern "C" void kernel_launch(void* const* d_in, const int* in_sizes, int n_in,
                              void* d_out, int out_size, void* d_ws, size_t ws_size,
                              hipStream_t stream) {
    const float* x  = (const float*)d_in[0];
    const float* kk = (const float*)d_in[1];
    float* out      = (float*)d_out;
    if (ws_size >= WS_NEED) {
        uint2*    xq  = (uint2*)d_ws;
        uint4*    tbl = (uint4*)((char*)d_ws + XQ_BYTES);
        uint32_t* rmx = (uint32_t*)((char*)d_ws + XQ_BYTES + TBL_BYTES);
        setup_all<<<dim3(XQWB + OCN), dim3(256), 0, stream>>>(x, kk, xq, tbl, rmx);
        semiconv_p<<<dim3(8 * OCN * 24), dim3(192), 0, stream>>>(
            (const char*)xq, tbl, rmx, out);
    } else {
        semiconv2d_f32<<<dim3(8 * 48 * 8), dim3(192), 0, stream>>>(x, kk, out);
    }
}

// Round 5
// 91.312 us; speedup vs baseline: 1.0413x; 1.0413x over previous
//
#include <hip/hip_runtime.h>
#include <math.h>
#include <stdint.h>

// SemiConv2d tropical conv: out = max_{ic,kh,kw} min(x_pad, K). f16-packed.
// R18: XCD-RESIDENT PARTITIONING. Post-mortems R14-R17: fewer loads
// (neutral), fewer waves (hurt), fewer bytes (helped ~proportionally),
// manual SW pipeline (hurt, compiler schedules better). Yet every
// throughput floor (VALU ~7us, L1 ~6us, L2-bytes ~7us) is 4-5x below
// the ~38us main measured -> uniform stall untouched by instruction
// restructuring. The conserved property: hp-fastest block order spreads
// same-(n,oc) across XCDs, so EVERY per-XCD L2 (4MB, non-shared) touches
// ALL 4.8MB of xq + output stream = over-subscribed -> gathers miss to
// L3 (~500-700cy) forever. R18: n = blockIdx%8 -> round-robin dispatch
// (measured m09) pins one n per XCD; per-XCD working set = 627KB slice
// + 52KB tables = L2-resident. Loads -> ~150cy L2 hits, hidden by 6
// waves/SIMD. ONLY the index decomposition changed vs R16 (R17 pipeline
// reverted: it cost +5.8us). Predict: main 38 -> 12-18us, total 89.3 ->
// 72-78us, absmax exactly 0.015625. If >=85: residency theory dead ->
// next: dwordx3 windows, 4 outputs/lane, halve load-instr per output.
// Budget: ~43us harness ws re-poison fill (268MB @80% peak, irreducible)
// + setup ~8 + main + gaps.

#define HH 96
#define WW 96
#define CIN 32
#define OCN 32
#define XQ_ROWS 98
#define ROWB 200                                // bytes per padded row (98 f16 + pad)
#define SLICEB (XQ_ROWS * ROWB)                 // 19600 B per (n,ic) slice
#define XQ_BYTES ((size_t)256 * SLICEB)         // 5,017,600 B
#define ROWU2 25                                // uint2 (8B) per row
#define XQW_TOTAL (256 * XQ_ROWS * ROWU2)       // 627,200 setup threads
#define XQWB (XQW_TOTAL / 256)                  // 2450 pack blocks
#define NROW 96                                 // sorted row-entries per oc
#define TBL_BYTES ((size_t)OCN * NROW * 16)
#define RMX_BYTES ((size_t)OCN * NROW * 4)
#define WS_NEED (XQ_BYTES + TBL_BYTES + RMX_BYTES)
#define NEGH2 0xFC00FC00u

typedef _Float16 h2 __attribute__((ext_vector_type(2)));
typedef uint32_t u2a4 __attribute__((ext_vector_type(2), aligned(4)));

__device__ __forceinline__ uint32_t pkmin_vs(uint32_t x, uint32_t k) {
    uint32_t d;
    asm("v_pk_min_f16 %0, %1, %2" : "=v"(d) : "v"(x), "s"(k));
    return d;
}
__device__ __forceinline__ uint32_t pkmin_vv(uint32_t a, uint32_t b) {
    uint32_t d;
    asm("v_pk_min_f16 %0, %1, %2" : "=v"(d) : "v"(a), "v"(b));
    return d;
}
__device__ __forceinline__ uint32_t pkmax(uint32_t a, uint32_t b) {
    uint32_t d;
    asm("v_pk_max_f16 %0, %1, %2" : "=v"(d) : "v"(a), "v"(b));
    return d;
}
__device__ __forceinline__ uint32_t packh2(float lo, float hi) {
    h2 p = {(_Float16)lo, (_Float16)hi};
    return __builtin_bit_cast(uint32_t, p);
}

// Fused setup (identical to R16).
// Blocks [0, XQWB): pack x -> compact xq. Row (s, hp): 98 f16 covering
//   w = -1..96 at bytes 0..195 (+4B pad), value = x[s][hp-1][w] or -inf.
// Blocks [XQWB, XQWB+32): per-oc row table sorted by rowmax desc.
//   entry uint4 = {k0dup, k1dup, k2dup, byte_off of (ic,dh) row}
//   rmx[rank]  = rowmax dup (exit threshold bounds all remaining k).
__global__ __launch_bounds__(256) void setup_all(const float* __restrict__ x,
                                                 const float* __restrict__ kk,
                                                 uint2* __restrict__ xq,
                                                 uint4* __restrict__ tbl,
                                                 uint32_t* __restrict__ rmx) {
    __shared__ float rs[NROW];
    const int bb = blockIdx.x;
    if (bb < XQWB) {
        int idx = bb * 256 + threadIdx.x;       // over 256*98*25
        int j8 = idx % ROWU2;                   // 8B unit in row
        int t  = idx / ROWU2;
        int hp = t % XQ_ROWS;
        int s  = t / XQ_ROWS;
        int h  = hp - 1;
        bool hv = (h >= 0) && (h < HH);
        const float* row = x + ((size_t)s * HH + (hv ? h : 0)) * WW;
        float v[4];
#pragma unroll
        for (int q = 0; q < 4; ++q) {
            int w = 4 * j8 - 1 + q;
            v[q] = (hv && w >= 0 && w < WW) ? row[w] : -INFINITY;
        }
        uint2 o;
        o.x = packh2(v[0], v[1]);
        o.y = packh2(v[2], v[3]);
        xq[idx] = o;
        return;
    }
    // ---- table path ----
    const int oc = bb - XQWB;
    const int t  = threadIdx.x;
    if (t >= NROW) return;
    const int ic = t / 3, dh = t - 3 * ic;
    const float* kp = kk + ((size_t)(oc * CIN + ic) * 3 + dh) * 3;
    float k0 = kp[0], k1 = kp[1], k2 = kp[2];
    float rm = fmaxf(fmaxf(k0, k1), k2);
    rs[t] = rm;
    __syncthreads();
    int rank = 0;
    for (int s = 0; s < NROW; ++s) {
        float v = rs[s];
        rank += (v > rm) || (v == rm && s < t);
    }
    uint32_t off = (uint32_t)(ic * XQ_ROWS + dh) * ROWB;
    tbl[oc * NROW + rank] = make_uint4(packh2(k0, k0), packh2(k1, k1),
                                       packh2(k2, k2), off);
    rmx[oc * NROW + rank] = packh2(rm, rm);
}

__global__ __launch_bounds__(192, 8) void semiconv_c(const char* __restrict__ xqb,
                                                     const uint4* __restrict__ tbl,
                                                     const uint32_t* __restrict__ rmx,
                                                     float* __restrict__ out) {
    const int tid = threadIdx.x;
    const int jj = tid % 48;          // w-pair 0..47
    const int hr = tid / 48;          // 0..3
    const int b  = blockIdx.x;
    // XCD-resident decomposition: n FASTEST (= b%8 = XCD via round-robin
    // dispatch). Each XCD touches exactly one 627KB n-slice -> L2-resident.
    const int n  = b & 7;
    const int t  = b >> 3;
    const int oc = t & 31;
    const int hp = t >> 5;            // 0..23
    const int h  = hp * 4 + hr;       // one output row per thread (2 w)

    const char* xqn = xqb + (size_t)n * CIN * SLICEB;   // uniform
    const int vbyte = h * ROWB + 4 * jj;                // per-lane
    const uint4* tb = tbl + oc * NROW;
    const uint32_t* rb = rmx + oc * NROW;

    uint32_t acc = NEGH2;

    for (int c = 0; c < NROW / 4; ++c) {
        // uniform scalar loads: 64B entry group (+ next-group threshold)
        uint4 e0 = tb[4 * c], e1 = tb[4 * c + 1], e2 = tb[4 * c + 2], e3 = tb[4 * c + 3];
        uint32_t kn = (c < NROW / 4 - 1) ? rb[4 * c + 4] : 0u;

        const char* r0 = xqn + e0.w;  // uniform bases -> saddr + v(vbyte)
        const char* r1 = xqn + e1.w;
        const char* r2 = xqn + e2.w;
        const char* r3 = xqn + e3.w;
        u2a4 q0 = *(const u2a4*)(r0 + vbyte);
        u2a4 q1 = *(const u2a4*)(r1 + vbyte);
        u2a4 q2 = *(const u2a4*)(r2 + vbyte);
        u2a4 q3 = *(const u2a4*)(r3 + vbyte);
        uint32_t v0 = __builtin_amdgcn_alignbit(q0.y, q0.x, 16);
        uint32_t v1 = __builtin_amdgcn_alignbit(q1.y, q1.x, 16);
        uint32_t v2 = __builtin_amdgcn_alignbit(q2.y, q2.x, 16);
        uint32_t v3 = __builtin_amdgcn_alignbit(q3.y, q3.x, 16);
        uint32_t m0 = pkmax(pkmax(pkmin_vs(q0.x, e0.x), pkmin_vs(v0, e0.y)),
                            pkmin_vs(q0.y, e0.z));
        uint32_t m1 = pkmax(pkmax(pkmin_vs(q1.x, e1.x), pkmin_vs(v1, e1.y)),
                            pkmin_vs(q1.y, e1.z));
        uint32_t m2 = pkmax(pkmax(pkmin_vs(q2.x, e2.x), pkmin_vs(v2, e2.y)),
                            pkmin_vs(q2.y, e2.z));
        uint32_t m3 = pkmax(pkmax(pkmin_vs(q3.x, e3.x), pkmin_vs(v3, e3.y)),
                            pkmin_vs(q3.y, e3.z));
        acc = pkmax(acc, pkmax(pkmax(m0, m1), pkmax(m2, m3)));

        if (c < NROW / 4 - 1) {
            // done iff min(acc.lo, acc.hi) >= next rowmax (max of remaining)
            uint32_t sw = __builtin_amdgcn_alignbit(acc, acc, 16);
            uint32_t mn = pkmin_vv(acc, sw);
            h2 a  = __builtin_bit_cast(h2, mn);
            h2 kv = __builtin_bit_cast(h2, kn);
            if (__all(a.x >= kv.x)) break;
        }
    }

    h2 a = __builtin_bit_cast(h2, acc);
    float2 v = make_float2((float)a.x, (float)a.y);
    *(float2*)(out + (((size_t)(n * OCN + oc)) * HH + h) * WW + 2 * jj) = v;
}

// ---------- f32 fallback if ws is too small ----------
#define NEGINF (-INFINITY)
__global__ __launch_bounds__(192, 8) void semiconv2d_f32(
    const float* __restrict__ x, const float* __restrict__ kk, float* __restrict__ out)
{
    const int tid = threadIdx.x;
    const int w  = tid % WW;
    const int hr = tid / WW;
    const int b   = blockIdx.x;
    const int ocb = b & 7;
    const int hp  = (b >> 3) % 48;
    const int n   = (b >> 3) / 48;
    const int h   = hp * 2 + hr;
    const int oc0 = ocb * 4;
    float a0[4], a1[4], a2[4];
#pragma unroll
    for (int i = 0; i < 4; ++i) { a0[i] = NEGINF; a1[i] = NEGINF; a2[i] = NEGINF; }
    const bool vm = (h > 0), vp = (h < HH - 1);
    const int hm  = vm ? h - 1 : h;
    const int hpl = vp ? h + 1 : h;
    const int cm  = (w > 0) ? -1 : 0;
    const int cp  = (w < WW - 1) ? 1 : 0;
    const float* rm = x + ((size_t)(n * CIN) * HH + hm)  * WW + w;
    const float* r1 = x + ((size_t)(n * CIN) * HH + h)   * WW + w;
    const float* rp = x + ((size_t)(n * CIN) * HH + hpl) * WW + w;
#pragma unroll 2
    for (int ic = 0; ic < CIN; ++ic) {
        float r00 = vm ? rm[cm] : NEGINF, r01 = vm ? rm[0] : NEGINF, r02 = vm ? rm[cp] : NEGINF;
        float r10 = r1[cm], r11 = r1[0], r12 = r1[cp];
        float r20 = vp ? rp[cm] : NEGINF, r21 = vp ? rp[0] : NEGINF, r22 = vp ? rp[cp] : NEGINF;
#pragma unroll
        for (int oc = 0; oc < 4; ++oc) {
            const float* kq = kk + (size_t)(((oc0 + oc) * CIN + ic)) * 9;
            a0[oc] = fmaxf(fmaxf(a0[oc], fminf(r00, kq[0])), fmaxf(fminf(r10, kq[3]), fminf(r20, kq[6])));
            a1[oc] = fmaxf(fmaxf(a1[oc], fminf(r01, kq[1])), fmaxf(fminf(r11, kq[4]), fminf(r21, kq[7])));
            a2[oc] = fmaxf(fmaxf(a2[oc], fminf(r02, kq[2])), fmaxf(fminf(r12, kq[5]), fminf(r22, kq[8])));
        }
        rm += HH * WW; r1 += HH * WW; rp += HH * WW;
    }
#pragma unroll
    for (int oc = 0; oc < 4; ++oc) {
        float v0 = (w > 0)      ? a0[oc] : NEGINF;
        float v2 = (w < WW - 1) ? a2[oc] : NEGINF;
        out[(((size_t)(n * OCN + oc0 + oc)) * HH + h) * WW + w] = fmaxf(fmaxf(v0, a1[oc]), v2);
    }
}

extern "C" void kernel_launch(void* const* d_in, const int* in_sizes, int n_in,
                              void* d_out, int out_size, void* d_ws, size_t ws_size,
                              hipStream_t stream) {
    const float* x  = (const float*)d_in[0];
    const float* kk = (const float*)d_in[1];
    float* out      = (float*)d_out;
    if (ws_size >= WS_NEED) {
        uint2*    xq  = (uint2*)d_ws;
        uint4*    tbl = (uint4*)((char*)d_ws + XQ_BYTES);
        uint32_t* rmx = (uint32_t*)((char*)d_ws + XQ_BYTES + TBL_BYTES);
        setup_all<<<dim3(XQWB + OCN), dim3(256), 0, stream>>>(x, kk, xq, tbl, rmx);
        semiconv_c<<<dim3(8 * OCN * 24), dim3(192), 0, stream>>>(
            (const char*)xq, tbl, rmx, out);
    } else {
        semiconv2d_f32<<<dim3(8 * 48 * 8), dim3(192), 0, stream>>>(x, kk, out);
    }
}

// Round 7
// 88.165 us; speedup vs baseline: 1.0785x; 1.0357x over previous
//
#include <hip/hip_runtime.h>
#include <math.h>
#include <stdint.h>

// SemiConv2d tropical conv: out = max_{ic,kh,kw} min(x_pad, K). f16-packed.
// R19b: resubmit of R19 (round-6 bench died on container acquisition, not
// kernel). WIDE LANES - 8 px per lane, 16B-aligned loads. Ledger R13-R18:
// fewer loads ~neutral, fewer waves hurt, fewer bytes helped ~bytes,
// SW-pipeline hurt, XCD-residency dead (R18 +2.0). Remaining unmodeled
// pipe: VMEM ISSUE through per-CU TA/L1. Old shape: 2 px/lane, 1 load
// per row = 2 px/load, 8B windows at 4B offsets -> ~half the lanes split
// a 64B line -> ~8cy/wave-load; per-CU ~23K cy = 10-20us pure VMEM issue,
// untouched by R13-R18's changes (they conserved px/load). R19: lane
// covers 8 px; per row reads 18-px window (36B) = dwordx4 + dword, both
// 16B-aligned (ROWB 200->208=16x13, window base 16*wl) -> 4 px/load, 0
// splits. Wave-loads ~3x down. VALU/px unchanged. Floors: VALU ~8us,
// VMEM ~3-5us, 4.5 waves/SIMD. Exit bit-identical (per-oc rowmax-sorted,
// threshold now guards 512px/wave, few extra rows priced in). No manual
// pipeline (R17 lesson). Predict: main ~32 -> 11-14, total 91.3 -> 73-79,
// absmax exactly 0.015625. If >=85: VMEM model dead -> fixed costs
// (fill 44us + launches) dominate -> fuse kernels or declare roofline.

#define HH 96
#define WW 96
#define CIN 32
#define OCN 32
#define XQ_ROWS 98
#define ROWB 208                                // 104 f16: w=-1..102, 16B-aligned
#define SLICEB (XQ_ROWS * ROWB)                 // 20384 B per (n,ic) slice
#define XQ_BYTES ((size_t)256 * SLICEB)         // 5,218,304 B
#define ROWU4 13                                // 16B units per row
#define XQP_TOTAL (256 * XQ_ROWS * ROWU4)       // 326,144 pack threads
#define XQPB (XQP_TOTAL / 256)                  // 1274 pack blocks
#define NROW 96                                 // sorted row-entries per oc
#define TBL_BYTES ((size_t)OCN * NROW * 16)
#define RMX_BYTES ((size_t)OCN * NROW * 4)
#define WS_NEED (XQ_BYTES + TBL_BYTES + RMX_BYTES)
#define NEGH2 0xFC00FC00u

typedef _Float16 h2 __attribute__((ext_vector_type(2)));

__device__ __forceinline__ uint32_t pkmin_vs(uint32_t x, uint32_t k) {
    uint32_t d;
    asm("v_pk_min_f16 %0, %1, %2" : "=v"(d) : "v"(x), "s"(k));
    return d;
}
__device__ __forceinline__ uint32_t pkmin_vv(uint32_t a, uint32_t b) {
    uint32_t d;
    asm("v_pk_min_f16 %0, %1, %2" : "=v"(d) : "v"(a), "v"(b));
    return d;
}
__device__ __forceinline__ uint32_t pkmax(uint32_t a, uint32_t b) {
    uint32_t d;
    asm("v_pk_max_f16 %0, %1, %2" : "=v"(d) : "v"(a), "v"(b));
    return d;
}
__device__ __forceinline__ uint32_t packh2(float lo, float hi) {
    h2 p = {(_Float16)lo, (_Float16)hi};
    return __builtin_bit_cast(uint32_t, p);
}

// Fused setup.
// Blocks [0, XQPB): pack x -> xq. Row (s, hp): 104 f16, byte(w)=2(w+1),
//   w=-1..102, value = x[s][hp-1][w] or -inf (h or w out of range).
//   Thread u writes 16B unit = px w = 8u-1 .. 8u+6.
// Blocks [XQPB, XQPB+32): per-oc row table sorted by rowmax desc.
//   entry uint4 = {k0dup, k1dup, k2dup, byte_off of (ic,dh) row}
//   rmx[rank]  = rowmax dup (exit threshold bounds all remaining k).
__global__ __launch_bounds__(256) void setup_all(const float* __restrict__ x,
                                                 const float* __restrict__ kk,
                                                 uint4* __restrict__ xq,
                                                 uint4* __restrict__ tbl,
                                                 uint32_t* __restrict__ rmx) {
    __shared__ float rs[NROW];
    const int bb = blockIdx.x;
    if (bb < XQPB) {
        int idx = bb * 256 + threadIdx.x;       // over 256*98*13
        int u  = idx % ROWU4;                   // 16B unit in row
        int t  = idx / ROWU4;
        int hp = t % XQ_ROWS;
        int s  = t / XQ_ROWS;
        int h  = hp - 1;
        bool hv = (h >= 0) && (h < HH);
        const float* row = x + ((size_t)s * HH + (hv ? h : 0)) * WW;
        float v[8];
#pragma unroll
        for (int q = 0; q < 8; ++q) {
            int w = 8 * u - 1 + q;
            v[q] = (hv && w >= 0 && w < WW) ? row[w] : -INFINITY;
        }
        uint4 o;
        o.x = packh2(v[0], v[1]);
        o.y = packh2(v[2], v[3]);
        o.z = packh2(v[4], v[5]);
        o.w = packh2(v[6], v[7]);
        xq[idx] = o;
        return;
    }
    // ---- table path ----
    const int oc = bb - XQPB;
    const int t  = threadIdx.x;
    if (t >= NROW) return;
    const int ic = t / 3, dh = t - 3 * ic;
    const float* kp = kk + ((size_t)(oc * CIN + ic) * 3 + dh) * 3;
    float k0 = kp[0], k1 = kp[1], k2 = kp[2];
    float rm = fmaxf(fmaxf(k0, k1), k2);
    rs[t] = rm;
    __syncthreads();
    int rank = 0;
    for (int s = 0; s < NROW; ++s) {
        float v = rs[s];
        rank += (v > rm) || (v == rm && s < t);
    }
    uint32_t off = (uint32_t)(ic * XQ_ROWS + dh) * ROWB;
    tbl[oc * NROW + rank] = make_uint4(packh2(k0, k0), packh2(k1, k1),
                                       packh2(k2, k2), off);
    rmx[oc * NROW + rank] = packh2(rm, rm);
}

// Lane = 8 outputs (w = 8*wl .. 8*wl+7) of one h row. Per sorted row:
// dwordx4 + dword (36B window, 16B-aligned), dwords d0..d4 where
// d_q = px (w0-1+2q, w0+2q). Pair p: kw0 = d_p, kw1 = align(d_{p+1},d_p),
// kw2 = d_{p+1}.
__global__ __launch_bounds__(192, 8) void semiconv_w(const char* __restrict__ xqb,
                                                     const uint4* __restrict__ tbl,
                                                     const uint32_t* __restrict__ rmx,
                                                     float* __restrict__ out) {
    const int tid = threadIdx.x;
    const int wl = tid % 12;          // 8-px group 0..11
    const int hh = tid / 12;          // 0..15
    const int b  = blockIdx.x;
    const int oc = b & 31;            // oc fastest: consecutive blocks share xq rows
    const int r  = b >> 5;
    const int hq = r % 6;
    const int n  = r / 6;
    const int h  = hq * 16 + hh;

    const char* xqn = xqb + (size_t)n * CIN * SLICEB;   // uniform
    const int vb = h * ROWB + 16 * wl;                  // per-lane, 16B-aligned
    const uint4* tb = tbl + oc * NROW;
    const uint32_t* rb = rmx + oc * NROW;

    uint32_t a0 = NEGH2, a1 = NEGH2, a2 = NEGH2, a3 = NEGH2;

    for (int c = 0; c < NROW / 2; ++c) {
        uint4 e0 = tb[2 * c], e1 = tb[2 * c + 1];       // uniform s_load 32B
        uint32_t kn = (c < NROW / 2 - 1) ? rb[2 * c + 2] : 0u;

        const char* r0 = xqn + e0.w;  // uniform base -> saddr + v(vb)
        const char* r1 = xqn + e1.w;
        uint4    d  = *(const uint4*)(r0 + vb);
        uint32_t d4 = *(const uint32_t*)(r0 + vb + 16);
        uint4    D  = *(const uint4*)(r1 + vb);
        uint32_t D4 = *(const uint32_t*)(r1 + vb + 16);

        // row 0
        uint32_t p01 = __builtin_amdgcn_alignbit(d.y, d.x, 16);
        uint32_t p12 = __builtin_amdgcn_alignbit(d.z, d.y, 16);
        uint32_t p23 = __builtin_amdgcn_alignbit(d.w, d.z, 16);
        uint32_t p34 = __builtin_amdgcn_alignbit(d4,  d.w, 16);
        a0 = pkmax(a0, pkmax(pkmax(pkmin_vs(d.x, e0.x), pkmin_vs(p01, e0.y)),
                             pkmin_vs(d.y, e0.z)));
        a1 = pkmax(a1, pkmax(pkmax(pkmin_vs(d.y, e0.x), pkmin_vs(p12, e0.y)),
                             pkmin_vs(d.z, e0.z)));
        a2 = pkmax(a2, pkmax(pkmax(pkmin_vs(d.z, e0.x), pkmin_vs(p23, e0.y)),
                             pkmin_vs(d.w, e0.z)));
        a3 = pkmax(a3, pkmax(pkmax(pkmin_vs(d.w, e0.x), pkmin_vs(p34, e0.y)),
                             pkmin_vs(d4,  e0.z)));
        // row 1
        uint32_t q01 = __builtin_amdgcn_alignbit(D.y, D.x, 16);
        uint32_t q12 = __builtin_amdgcn_alignbit(D.z, D.y, 16);
        uint32_t q23 = __builtin_amdgcn_alignbit(D.w, D.z, 16);
        uint32_t q34 = __builtin_amdgcn_alignbit(D4,  D.w, 16);
        a0 = pkmax(a0, pkmax(pkmax(pkmin_vs(D.x, e1.x), pkmin_vs(q01, e1.y)),
                             pkmin_vs(D.y, e1.z)));
        a1 = pkmax(a1, pkmax(pkmax(pkmin_vs(D.y, e1.x), pkmin_vs(q12, e1.y)),
                             pkmin_vs(D.z, e1.z)));
        a2 = pkmax(a2, pkmax(pkmax(pkmin_vs(D.z, e1.x), pkmin_vs(q23, e1.y)),
                             pkmin_vs(D.w, e1.z)));
        a3 = pkmax(a3, pkmax(pkmax(pkmin_vs(D.w, e1.x), pkmin_vs(q34, e1.y)),
                             pkmin_vs(D4,  e1.z)));

        if (c < NROW / 2 - 1) {
            // done iff min over all 8 px (both halves) >= next rowmax
            uint32_t mn = pkmin_vv(pkmin_vv(a0, a1), pkmin_vv(a2, a3));
            mn = pkmin_vv(mn, __builtin_amdgcn_alignbit(mn, mn, 16));
            h2 a  = __builtin_bit_cast(h2, mn);
            h2 kv = __builtin_bit_cast(h2, kn);
            if (__all(a.x >= kv.x)) break;
        }
    }

    float* ob = out + (((size_t)(n * OCN + oc)) * HH + h) * WW + 8 * wl;
    h2 r0 = __builtin_bit_cast(h2, a0);
    h2 r1 = __builtin_bit_cast(h2, a1);
    h2 r2 = __builtin_bit_cast(h2, a2);
    h2 r3 = __builtin_bit_cast(h2, a3);
    float4 o1 = make_float4((float)r0.x, (float)r0.y, (float)r1.x, (float)r1.y);
    float4 o2 = make_float4((float)r2.x, (float)r2.y, (float)r3.x, (float)r3.y);
    *(float4*)(ob)     = o1;
    *(float4*)(ob + 4) = o2;
}

// ---------- f32 fallback if ws is too small ----------
#define NEGINF (-INFINITY)
__global__ __launch_bounds__(192, 8) void semiconv2d_f32(
    const float* __restrict__ x, const float* __restrict__ kk, float* __restrict__ out)
{
    const int tid = threadIdx.x;
    const int w  = tid % WW;
    const int hr = tid / WW;
    const int b   = blockIdx.x;
    const int ocb = b & 7;
    const int hp  = (b >> 3) % 48;
    const int n   = (b >> 3) / 48;
    const int h   = hp * 2 + hr;
    const int oc0 = ocb * 4;
    float a0[4], a1[4], a2[4];
#pragma unroll
    for (int i = 0; i < 4; ++i) { a0[i] = NEGINF; a1[i] = NEGINF; a2[i] = NEGINF; }
    const bool vm = (h > 0), vp = (h < HH - 1);
    const int hm  = vm ? h - 1 : h;
    const int hpl = vp ? h + 1 : h;
    const int cm  = (w > 0) ? -1 : 0;
    const int cp  = (w < WW - 1) ? 1 : 0;
    const float* rm = x + ((size_t)(n * CIN) * HH + hm)  * WW + w;
    const float* r1 = x + ((size_t)(n * CIN) * HH + h)   * WW + w;
    const float* rp = x + ((size_t)(n * CIN) * HH + hpl) * WW + w;
#pragma unroll 2
    for (int ic = 0; ic < CIN; ++ic) {
        float r00 = vm ? rm[cm] : NEGINF, r01 = vm ? rm[0] : NEGINF, r02 = vm ? rm[cp] : NEGINF;
        float r10 = r1[cm], r11 = r1[0], r12 = r1[cp];
        float r20 = vp ? rp[cm] : NEGINF, r21 = vp ? rp[0] : NEGINF, r22 = vp ? rp[cp] : NEGINF;
#pragma unroll
        for (int oc = 0; oc < 4; ++oc) {
            const float* kq = kk + (size_t)(((oc0 + oc) * CIN + ic)) * 9;
            a0[oc] = fmaxf(fmaxf(a0[oc], fminf(r00, kq[0])), fmaxf(fminf(r10, kq[3]), fminf(r20, kq[6])));
            a1[oc] = fmaxf(fmaxf(a1[oc], fminf(r01, kq[1])), fmaxf(fminf(r11, kq[4]), fminf(r21, kq[7])));
            a2[oc] = fmaxf(fmaxf(a2[oc], fminf(r02, kq[2])), fmaxf(fminf(r12, kq[5]), fminf(r22, kq[8])));
        }
        rm += HH * WW; r1 += HH * WW; rp += HH * WW;
    }
#pragma unroll
    for (int oc = 0; oc < 4; ++oc) {
        float v0 = (w > 0)      ? a0[oc] : NEGINF;
        float v2 = (w < WW - 1) ? a2[oc] : NEGINF;
        out[(((size_t)(n * OCN + oc0 + oc)) * HH + h) * WW + w] = fmaxf(fmaxf(v0, a1[oc]), v2);
    }
}

extern "C" void kernel_launch(void* const* d_in, const int* in_sizes, int n_in,
                              void* d_out, int out_size, void* d_ws, size_t ws_size,
                              hipStream_t stream) {
    const float* x  = (const float*)d_in[0];
    const float* kk = (const float*)d_in[1];
    float* out      = (float*)d_out;
    if (ws_size >= WS_NEED) {
        uint4*    xq  = (uint4*)d_ws;
        uint4*    tbl = (uint4*)((char*)d_ws + XQ_BYTES);
        uint32_t* rmx = (uint32_t*)((char*)d_ws + XQ_BYTES + TBL_BYTES);
        setup_all<<<dim3(XQPB + OCN), dim3(256), 0, stream>>>(x, kk, xq, tbl, rmx);
        semiconv_w<<<dim3(8 * OCN * 6), dim3(192), 0, stream>>>(
            (const char*)xq, tbl, rmx, out);
    } else {
        semiconv2d_f32<<<dim3(8 * 48 * 8), dim3(192), 0, stream>>>(x, kk, out);
    }
}

// Round 8
// 86.686 us; speedup vs baseline: 1.0969x; 1.0171x over previous
//
#include <hip/hip_runtime.h>
#include <math.h>
#include <stdint.h>

// SemiConv2d tropical conv: out = max_{ic,kh,kw} min(x_pad, K). f16-packed.
// R20: LDS-STAGED TILE, 8 ocs share it; 6 px/lane (one 16B window per
// row = all 3 kw taps). Ledger R13-R19: fewer loads X, fewer waves X,
// fewer bytes ~proportional, SW-pipeline X, XCD-residency X, aligned
// wide loads X (R19 -3us only). Main pinned ~30us vs ~8-12us floors.
// Surviving theory: GATHER VOLUME - ~130K wave-iters x 2.5KB = ~330MB
// through L2/L3 at L3-gather BW ~12TB/s = ~27us = measured. No blockIdx
// partition made it L2-resident (R18: mapping assumption unverified).
// R20 makes locality structural: block = (n, 4 h-rows, 8 ocs) = 512 thr;
// stage 6 xq rows x 32 ic = 39.9KB in LDS ONCE; each wave (one oc,
// 16wl x 4hr) scans sorted rows from LDS. Per iter: 2 LDS reads + 2
// s_load + ~50 VALU -> VALU-bound ~7.5us + staging ~3. 6144 waves
// (24/CU), 3-4 blocks/CU by LDS. Exit unchanged (per-oc rowmax sorted,
// 384px/wave) -> absmax exactly 0.015625.
// Predict: main 30 -> 10-14, total 88.2 -> 72-78. If >=85: cost is not
// data motion; fixed costs (fill ~46 + setup + gaps) dominate ->
// declare roofline.

#define HH 96
#define WW 96
#define CIN 32
#define OCN 32
#define XQ_ROWS 98
#define ROWB 208                                // 104 f16: w=-1..102, 16B units
#define ROWU4 13                                // 16B units per row
#define SLICEB (XQ_ROWS * ROWB)                 // 20384 B per (n,ic) slice
#define XQ_BYTES ((size_t)256 * SLICEB)         // 5,218,304 B
#define XQP_TOTAL (256 * XQ_ROWS * ROWU4)       // 326,144 pack threads
#define XQPB (XQP_TOTAL / 256)                  // 1274 pack blocks
#define NROW 96                                 // sorted row-entries per oc
#define TBL_BYTES ((size_t)OCN * NROW * 16)
#define RMX_BYTES ((size_t)OCN * NROW * 4)
#define WS_NEED (XQ_BYTES + TBL_BYTES + RMX_BYTES)
#define NEGH2 0xFC00FC00u
#define LDSU 2496                               // 32 ic * 6 rows * 13 units

typedef _Float16 h2 __attribute__((ext_vector_type(2)));
typedef uint32_t u4a4 __attribute__((ext_vector_type(4), aligned(4)));

__device__ __forceinline__ uint32_t pkmin_vs(uint32_t x, uint32_t k) {
    uint32_t d;
    asm("v_pk_min_f16 %0, %1, %2" : "=v"(d) : "v"(x), "s"(k));
    return d;
}
__device__ __forceinline__ uint32_t pkmin_vv(uint32_t a, uint32_t b) {
    uint32_t d;
    asm("v_pk_min_f16 %0, %1, %2" : "=v"(d) : "v"(a), "v"(b));
    return d;
}
__device__ __forceinline__ uint32_t pkmax(uint32_t a, uint32_t b) {
    uint32_t d;
    asm("v_pk_max_f16 %0, %1, %2" : "=v"(d) : "v"(a), "v"(b));
    return d;
}
__device__ __forceinline__ uint32_t packh2(float lo, float hi) {
    h2 p = {(_Float16)lo, (_Float16)hi};
    return __builtin_bit_cast(uint32_t, p);
}

// Fused setup.
// Blocks [0, XQPB): pack x -> xq. Row (s, hp): 104 f16, byte(w)=2(w+1),
//   w=-1..102, value = x[s][hp-1][w] or -inf. Thread u: 16B unit =
//   px w = 8u-1 .. 8u+6.
// Blocks [XQPB, XQPB+32): per-oc row table sorted by rowmax desc.
//   entry uint4 = {k0dup, k1dup, k2dup, LOCAL byte off (ic*6+dh)*208}
//   rmx[rank]  = rowmax dup (exit threshold bounds all remaining k).
__global__ __launch_bounds__(256) void setup_all(const float* __restrict__ x,
                                                 const float* __restrict__ kk,
                                                 uint4* __restrict__ xq,
                                                 uint4* __restrict__ tbl,
                                                 uint32_t* __restrict__ rmx) {
    __shared__ float rs[NROW];
    const int bb = blockIdx.x;
    if (bb < XQPB) {
        int idx = bb * 256 + threadIdx.x;       // over 256*98*13
        int u  = idx % ROWU4;                   // 16B unit in row
        int t  = idx / ROWU4;
        int hp = t % XQ_ROWS;
        int s  = t / XQ_ROWS;
        int h  = hp - 1;
        bool hv = (h >= 0) && (h < HH);
        const float* row = x + ((size_t)s * HH + (hv ? h : 0)) * WW;
        float v[8];
#pragma unroll
        for (int q = 0; q < 8; ++q) {
            int w = 8 * u - 1 + q;
            v[q] = (hv && w >= 0 && w < WW) ? row[w] : -INFINITY;
        }
        uint4 o;
        o.x = packh2(v[0], v[1]);
        o.y = packh2(v[2], v[3]);
        o.z = packh2(v[4], v[5]);
        o.w = packh2(v[6], v[7]);
        xq[idx] = o;
        return;
    }
    // ---- table path ----
    const int oc = bb - XQPB;
    const int t  = threadIdx.x;
    if (t >= NROW) return;
    const int ic = t / 3, dh = t - 3 * ic;
    const float* kp = kk + ((size_t)(oc * CIN + ic) * 3 + dh) * 3;
    float k0 = kp[0], k1 = kp[1], k2 = kp[2];
    float rm = fmaxf(fmaxf(k0, k1), k2);
    rs[t] = rm;
    __syncthreads();
    int rank = 0;
    for (int s = 0; s < NROW; ++s) {
        float v = rs[s];
        rank += (v > rm) || (v == rm && s < t);
    }
    uint32_t off = (uint32_t)(ic * 6 + dh) * ROWB;  // LOCAL offset in LDS tile
    tbl[oc * NROW + rank] = make_uint4(packh2(k0, k0), packh2(k1, k1),
                                       packh2(k2, k2), off);
    rmx[oc * NROW + rank] = packh2(rm, rm);
}

// Block = (n, 4 output h-rows, 8 ocs), 512 threads = 8 waves.
// Stage 6 xq rows (hp = h0..h0+5) x 32 ic into LDS (39,936 B), barrier,
// then each wave (one oc) scans its sorted rows from LDS with early exit.
// Lane = 6 px: wl 0..15 (w0 = 6*wl), hr 0..3 (h = h0+hr). Per row one
// 16B window at local (ic*6+dh)*208 + hr*208 + 12*wl gives d0..d3;
// pair q: kw0=d_q, kw1=align(d_{q+1},d_q), kw2=d_{q+1}, q=0..2.
__global__ __launch_bounds__(512, 4) void semiconv_lds(const char* __restrict__ xqb,
                                                       const uint4* __restrict__ tbl,
                                                       const uint32_t* __restrict__ rmx,
                                                       float* __restrict__ out) {
    __shared__ uint4 lsd[LDSU];
    const int tid = threadIdx.x;
    const int b   = blockIdx.x;
    const int ocl = b & 3;
    const int t   = b >> 2;
    const int ht  = t % 24;
    const int n   = t / 24;
    const int h0  = ht * 4;

    // ---- stage 6 rows x 32 ic (2496 x 16B) ----
    const uint4* xg = (const uint4*)(xqb + (size_t)n * CIN * SLICEB);
#pragma unroll
    for (int i = 0; i < 5; ++i) {
        int u = tid + 512 * i;
        if (u < LDSU) {
            int ic = u / 78;                    // 6*13 units per ic
            int rr = u - ic * 78;
            int r  = rr / 13;
            int j  = rr - r * 13;
            lsd[(ic * 6 + r) * 13 + j] = xg[(ic * 98 + h0 + r) * 13 + j];
        }
    }
    __syncthreads();

    const int lane = tid & 63;
    const int oc   = ocl * 8 + (tid >> 6);      // wave-uniform
    const int wl   = lane & 15;
    const int hr   = lane >> 4;
    const int h    = h0 + hr;
    const char* ldsb = (const char*)lsd;
    const int vb   = hr * ROWB + 12 * wl;       // per-lane byte offset
    const uint4* tb = tbl + oc * NROW;
    const uint32_t* rb = rmx + oc * NROW;

    uint32_t a0 = NEGH2, a1 = NEGH2, a2 = NEGH2;

    for (int c = 0; c < NROW / 2; ++c) {
        uint4 e0 = tb[2 * c], e1 = tb[2 * c + 1];   // uniform s_load
        uint32_t kn = (c < NROW / 2 - 1) ? rb[2 * c + 2] : 0u;

        u4a4 d = *(const u4a4*)(ldsb + e0.w + vb);
        u4a4 D = *(const u4a4*)(ldsb + e1.w + vb);

        uint32_t p01 = __builtin_amdgcn_alignbit(d.y, d.x, 16);
        uint32_t p12 = __builtin_amdgcn_alignbit(d.z, d.y, 16);
        uint32_t p23 = __builtin_amdgcn_alignbit(d.w, d.z, 16);
        a0 = pkmax(a0, pkmax(pkmax(pkmin_vs(d.x, e0.x), pkmin_vs(p01, e0.y)),
                             pkmin_vs(d.y, e0.z)));
        a1 = pkmax(a1, pkmax(pkmax(pkmin_vs(d.y, e0.x), pkmin_vs(p12, e0.y)),
                             pkmin_vs(d.z, e0.z)));
        a2 = pkmax(a2, pkmax(pkmax(pkmin_vs(d.z, e0.x), pkmin_vs(p23, e0.y)),
                             pkmin_vs(d.w, e0.z)));

        uint32_t q01 = __builtin_amdgcn_alignbit(D.y, D.x, 16);
        uint32_t q12 = __builtin_amdgcn_alignbit(D.z, D.y, 16);
        uint32_t q23 = __builtin_amdgcn_alignbit(D.w, D.z, 16);
        a0 = pkmax(a0, pkmax(pkmax(pkmin_vs(D.x, e1.x), pkmin_vs(q01, e1.y)),
                             pkmin_vs(D.y, e1.z)));
        a1 = pkmax(a1, pkmax(pkmax(pkmin_vs(D.y, e1.x), pkmin_vs(q12, e1.y)),
                             pkmin_vs(D.z, e1.z)));
        a2 = pkmax(a2, pkmax(pkmax(pkmin_vs(D.z, e1.x), pkmin_vs(q23, e1.y)),
                             pkmin_vs(D.w, e1.z)));

        if (c < NROW / 2 - 1) {
            // done iff min over all 6 px (both halves) >= next rowmax
            uint32_t mn = pkmin_vv(pkmin_vv(a0, a1), a2);
            mn = pkmin_vv(mn, __builtin_amdgcn_alignbit(mn, mn, 16));
            h2 a  = __builtin_bit_cast(h2, mn);
            h2 kv = __builtin_bit_cast(h2, kn);
            if (__all(a.x >= kv.x)) break;
        }
    }

    float* ob = out + (((size_t)(n * OCN + oc)) * HH + h) * WW + 6 * wl;
    h2 r0 = __builtin_bit_cast(h2, a0);
    h2 r1 = __builtin_bit_cast(h2, a1);
    h2 r2 = __builtin_bit_cast(h2, a2);
    *(float2*)(ob)     = make_float2((float)r0.x, (float)r0.y);
    *(float2*)(ob + 2) = make_float2((float)r1.x, (float)r1.y);
    *(float2*)(ob + 4) = make_float2((float)r2.x, (float)r2.y);
}

// ---------- f32 fallback if ws is too small ----------
#define NEGINF (-INFINITY)
__global__ __launch_bounds__(192, 8) void semiconv2d_f32(
    const float* __restrict__ x, const float* __restrict__ kk, float* __restrict__ out)
{
    const int tid = threadIdx.x;
    const int w  = tid % WW;
    const int hr = tid / WW;
    const int b   = blockIdx.x;
    const int ocb = b & 7;
    const int hp  = (b >> 3) % 48;
    const int n   = (b >> 3) / 48;
    const int h   = hp * 2 + hr;
    const int oc0 = ocb * 4;
    float a0[4], a1[4], a2[4];
#pragma unroll
    for (int i = 0; i < 4; ++i) { a0[i] = NEGINF; a1[i] = NEGINF; a2[i] = NEGINF; }
    const bool vm = (h > 0), vp = (h < HH - 1);
    const int hm  = vm ? h - 1 : h;
    const int hpl = vp ? h + 1 : h;
    const int cm  = (w > 0) ? -1 : 0;
    const int cp  = (w < WW - 1) ? 1 : 0;
    const float* rm = x + ((size_t)(n * CIN) * HH + hm)  * WW + w;
    const float* r1 = x + ((size_t)(n * CIN) * HH + h)   * WW + w;
    const float* rp = x + ((size_t)(n * CIN) * HH + hpl) * WW + w;
#pragma unroll 2
    for (int ic = 0; ic < CIN; ++ic) {
        float r00 = vm ? rm[cm] : NEGINF, r01 = vm ? rm[0] : NEGINF, r02 = vm ? rm[cp] : NEGINF;
        float r10 = r1[cm], r11 = r1[0], r12 = r1[cp];
        float r20 = vp ? rp[cm] : NEGINF, r21 = vp ? rp[0] : NEGINF, r22 = vp ? rp[cp] : NEGINF;
#pragma unroll
        for (int oc = 0; oc < 4; ++oc) {
            const float* kq = kk + (size_t)(((oc0 + oc) * CIN + ic)) * 9;
            a0[oc] = fmaxf(fmaxf(a0[oc], fminf(r00, kq[0])), fmaxf(fminf(r10, kq[3]), fminf(r20, kq[6])));
            a1[oc] = fmaxf(fmaxf(a1[oc], fminf(r01, kq[1])), fmaxf(fminf(r11, kq[4]), fminf(r21, kq[7])));
            a2[oc] = fmaxf(fmaxf(a2[oc], fminf(r02, kq[2])), fmaxf(fminf(r12, kq[5]), fminf(r22, kq[8])));
        }
        rm += HH * WW; r1 += HH * WW; rp += HH * WW;
    }
#pragma unroll
    for (int oc = 0; oc < 4; ++oc) {
        float v0 = (w > 0)      ? a0[oc] : NEGINF;
        float v2 = (w < WW - 1) ? a2[oc] : NEGINF;
        out[(((size_t)(n * OCN + oc0 + oc)) * HH + h) * WW + w] = fmaxf(fmaxf(v0, a1[oc]), v2);
    }
}

extern "C" void kernel_launch(void* const* d_in, const int* in_sizes, int n_in,
                              void* d_out, int out_size, void* d_ws, size_t ws_size,
                              hipStream_t stream) {
    const float* x  = (const float*)d_in[0];
    const float* kk = (const float*)d_in[1];
    float* out      = (float*)d_out;
    if (ws_size >= WS_NEED) {
        uint4*    xq  = (uint4*)d_ws;
        uint4*    tbl = (uint4*)((char*)d_ws + XQ_BYTES);
        uint32_t* rmx = (uint32_t*)((char*)d_ws + XQ_BYTES + TBL_BYTES);
        setup_all<<<dim3(XQPB + OCN), dim3(256), 0, stream>>>(x, kk, xq, tbl, rmx);
        semiconv_lds<<<dim3(4 * 24 * 8), dim3(512), 0, stream>>>(
            (const char*)xq, tbl, rmx, out);
    } else {
        semiconv2d_f32<<<dim3(8 * 48 * 8), dim3(192), 0, stream>>>(x, kk, out);
    }
}